// Round 1
// 1007.584 us; speedup vs baseline: 1.0012x; 1.0012x over previous
//
#include <hip/hip_runtime.h>

// Problem constants (reference: B=2048, E=32, N=32, D=64)
#define B_  2048
#define E_  32
#define N_  32
#define D_  64

typedef float f4 __attribute__((ext_vector_type(4)));

__device__ __forceinline__ float shflx(float v, int m) { return __shfl_xor(v, m, 64); }

// One WAVE per (b,e) tile. 4 waves (256 threads) per block, no __syncthreads.
// Tile = N*D = 2048 floats = 512 float4. Load instruction j reads float4
// index j*64 + lane  (1 KB contiguous per instruction, fully coalesced).
//   linear float4 f = j*64 + l  ->  n = f>>4 = j*4 + (l>>4),  d4 = f&15 = l&15
// So lane l (group g = l>>4, column d4 = l&15) holds, for j = 0..7:
//   rel/nv float4 of neighbor n = 4j+g at dims [4*d4, 4*d4+4).
__global__ __launch_bounds__(256) void kgcn_wave(
    const float* __restrict__ self_v,   // [B,E,D]
    const float* __restrict__ nv,       // [B,E,N,D]
    const float* __restrict__ rel,      // [B,E,N,D]
    const float* __restrict__ user,     // [B,D]
    const float* __restrict__ W,        // [D,D] row-major W[d][k]
    const float* __restrict__ blin,     // [D]
    float* __restrict__ out)            // [B,E,D]
{
    const int t  = threadIdx.x;
    const int w  = t >> 6;              // wave in block, 0..3
    const int l  = t & 63;              // lane
    const int g  = l >> 4;              // group 0..3  (n mod 4 == g)
    const int d4 = l & 15;              // float4 column 0..15

    const int be = blockIdx.x * 4 + w;  // 0 .. B*E-1
    const int b  = be >> 5;             // E = 32

    __shared__ f4 s_pre[4][16];         // per-wave pre-linear vector (1 KB total)

    const f4* rel4 = (const f4*)rel + (size_t)be * 512;
    const f4* nv4  = (const f4*)nv  + (size_t)be * 512;

    // ---- issue all global loads up front ----
    f4 u4 = ((const f4*)user)[b * 16 + d4];
    f4 r[8], v[8];
    #pragma unroll
    for (int j = 0; j < 8; ++j) r[j] = __builtin_nontemporal_load(&rel4[j * 64 + l]);
    #pragma unroll
    for (int j = 0; j < 8; ++j) v[j] = __builtin_nontemporal_load(&nv4[j * 64 + l]);
    f4 sv = ((const f4*)self_v)[(size_t)be * 16 + d4];

    // ---- phase 1: score[n] = (user . rel[n]) / D, n = 4j+g ----
    // partial dot over this lane's 4 dims, then butterfly over the 16 lanes
    // of the group (they cover d4 = 0..15 -> full D).
    float s[8];
    #pragma unroll
    for (int j = 0; j < 8; ++j) {
        float p = r[j].x * u4.x + r[j].y * u4.y + r[j].z * u4.z + r[j].w * u4.w;
        p += shflx(p, 1); p += shflx(p, 2); p += shflx(p, 4); p += shflx(p, 8);
        s[j] = p * (1.0f / (float)D_);
    }

    // ---- softmax over the 32 n's; each lane holds 8, groups tile n mod 4.
    // Cross-group butterfly (masks 16, 32) combines the 4 groups; intra-group
    // replication (low 4 lane bits) never enters the butterfly.
    float m = s[0];
    #pragma unroll
    for (int j = 1; j < 8; ++j) m = fmaxf(m, s[j]);
    m = fmaxf(m, shflx(m, 16));
    m = fmaxf(m, shflx(m, 32));

    float e[8];
    float sum = 0.0f;
    #pragma unroll
    for (int j = 0; j < 8; ++j) { e[j] = __expf(s[j] - m); sum += e[j]; }
    sum += shflx(sum, 16);
    sum += shflx(sum, 32);
    const float sc = 1.0f / (sum * (float)N_);   // fold the 1/N mean into attn

    // ---- phase 2: agg[d] = sum_n attn[n] * nv[n,d] ----
    f4 acc = (f4){0.0f, 0.0f, 0.0f, 0.0f};
    #pragma unroll
    for (int j = 0; j < 8; ++j) {
        const float a = e[j] * sc;                // attn(n=4j+g) / N
        acc.x += a * v[j].x;
        acc.y += a * v[j].y;
        acc.z += a * v[j].z;
        acc.w += a * v[j].w;
    }
    // reduce over the 4 groups (lanes ^16, ^32); result replicated, per d4
    acc.x += shflx(acc.x, 16); acc.y += shflx(acc.y, 16);
    acc.z += shflx(acc.z, 16); acc.w += shflx(acc.w, 16);
    acc.x += shflx(acc.x, 32); acc.y += shflx(acc.y, 32);
    acc.z += shflx(acc.z, 32); acc.w += shflx(acc.w, 32);

    // add self, stash pre-linear vector (wave-synchronous LDS: per-wave DS
    // ops are in-order, no __syncthreads needed; wave_barrier stops motion)
    acc.x += sv.x; acc.y += sv.y; acc.z += sv.z; acc.w += sv.w;
    if (g == 0) s_pre[w][d4] = acc;
    __builtin_amdgcn_wave_barrier();

    // ---- phase 3: out[l] = relu(b[l] + sum_k pre[k] * W[l][k]) ----
    // s_pre reads are same-address broadcasts (conflict-free); W rows are
    // L1-resident (16 KB) after the first tile per CU.
    float o = blin[l];
    const f4* Wrow = (const f4*)W + l * 16;
    #pragma unroll
    for (int k4 = 0; k4 < 16; ++k4) {
        f4 wv = Wrow[k4];
        f4 p  = s_pre[w][k4];
        o += wv.x * p.x + wv.y * p.y + wv.z * p.z + wv.w * p.w;
    }
    __builtin_nontemporal_store(fmaxf(o, 0.0f), &out[(size_t)be * 64 + l]);
}

extern "C" void kernel_launch(void* const* d_in, const int* in_sizes, int n_in,
                              void* d_out, int out_size, void* d_ws, size_t ws_size,
                              hipStream_t stream) {
    const float* self_v = (const float*)d_in[0];   // [B,E,D]
    const float* nv     = (const float*)d_in[1];   // [B,E,N,D]
    const float* rel    = (const float*)d_in[2];   // [B,E,N,D]
    const float* user   = (const float*)d_in[3];   // [B,D]
    // d_in[4] = masks (unused by the module)
    const float* W      = (const float*)d_in[5];   // [D,D]
    const float* blin   = (const float*)d_in[6];   // [D]
    float* out          = (float*)d_out;           // [B,E,D]

    const int blocks = (B_ * E_) / 4;              // 16384 blocks x 4 waves
    kgcn_wave<<<blocks, 256, 0, stream>>>(self_v, nv, rel, user, W, blin, out);
}